// Round 1
// baseline (1845.189 us; speedup 1.0000x reference)
//
#include <hip/hip_runtime.h>
#include <hip/hip_bf16.h>

#define DIM 1024
#define NUM_HEADS 16
#define HEAD_DIM 64
#define BATCH 2
#define SEQ 2048
#define M_ROWS (BATCH * SEQ)   // 4096

// ---------------- GEMM: C = A[M,K] @ W[K,N] + bias[N] ----------------
// head_layout=1: write C element (m,n) to [((b*H + n/64)*S + s)*64 + n%64]
// head_layout=0: normal row-major [m*N + n]
#define TM 64
#define TN 64
#define TK 16

__global__ __launch_bounds__(256) void gemm_bias(
    const float* __restrict__ A, const float* __restrict__ W,
    const float* __restrict__ bias, float* __restrict__ C,
    int M, int N, int K, int head_layout)
{
    __shared__ float As[TK][TM + 4];   // stored transposed: As[k][m]
    __shared__ float Ws[TK][TN + 4];

    const int t  = threadIdx.x;
    const int m0 = blockIdx.y * TM;
    const int n0 = blockIdx.x * TN;
    const int tm = (t >> 4) * 4;      // 0..60
    const int tn = (t & 15) * 4;      // 0..60

    // loader indices
    const int ar = t >> 2;            // 0..63  (row within A tile)
    const int ak = (t & 3) * 4;       // 0,4,8,12
    const int wr = t >> 4;            // 0..15  (k row within W tile)
    const int wn = (t & 15) * 4;      // 0..60

    float acc[4][4] = {};

    for (int k0 = 0; k0 < K; k0 += TK) {
        float4 av = *(const float4*)&A[(size_t)(m0 + ar) * K + k0 + ak];
        float4 wv = *(const float4*)&W[(size_t)(k0 + wr) * N + n0 + wn];
        __syncthreads();              // previous iter's compute done before overwrite
        As[ak + 0][ar] = av.x;
        As[ak + 1][ar] = av.y;
        As[ak + 2][ar] = av.z;
        As[ak + 3][ar] = av.w;
        *(float4*)&Ws[wr][wn] = wv;
        __syncthreads();
        #pragma unroll
        for (int kk = 0; kk < TK; ++kk) {
            float4 a4 = *(const float4*)&As[kk][tm];
            float4 b4 = *(const float4*)&Ws[kk][tn];
            float ar_[4] = {a4.x, a4.y, a4.z, a4.w};
            float br_[4] = {b4.x, b4.y, b4.z, b4.w};
            #pragma unroll
            for (int i = 0; i < 4; ++i)
                #pragma unroll
                for (int j = 0; j < 4; ++j)
                    acc[i][j] += ar_[i] * br_[j];
        }
    }

    float4 bias4 = *(const float4*)&bias[n0 + tn];
    float bv[4] = {bias4.x, bias4.y, bias4.z, bias4.w};

    #pragma unroll
    for (int i = 0; i < 4; ++i) {
        int m = m0 + tm + i;
        float4 r;
        r.x = acc[i][0] + bv[0];
        r.y = acc[i][1] + bv[1];
        r.z = acc[i][2] + bv[2];
        r.w = acc[i][3] + bv[3];
        if (!head_layout) {
            *(float4*)&C[(size_t)m * N + n0 + tn] = r;
        } else {
            int b = m / SEQ, s = m % SEQ;
            int n = n0 + tn;
            int h = n / HEAD_DIM, d = n % HEAD_DIM;
            *(float4*)&C[((size_t)(b * NUM_HEADS + h) * SEQ + s) * HEAD_DIM + d] = r;
        }
    }
}

// ---------------- Flash-style causal attention ----------------
// Q,K,V in [B,H,S,64] layout. ctx written as [B,S,DIM] (= [b][s][h*64+d]).
#define TQ 16
#define KB 64
#define PHD 68   // padded head-dim row (16B-aligned, bank-conflict friendly)

__global__ __launch_bounds__(256) void attn(
    const float* __restrict__ Q, const float* __restrict__ K,
    const float* __restrict__ V, float* __restrict__ ctx)
{
    __shared__ float Ks[KB][PHD];
    __shared__ float Vs[KB][PHD];
    __shared__ float Qs[TQ][PHD];
    __shared__ float Sc[TQ][KB];
    __shared__ float m_run[TQ], l_run[TQ], alpha_s[TQ];

    const int t  = threadIdx.x;
    const int qt = blockIdx.x % (SEQ / TQ);
    const int bh = blockIdx.x / (SEQ / TQ);
    const int q0 = qt * TQ;

    const float* Qp = Q + ((size_t)bh * SEQ + q0) * HEAD_DIM;
    const float* Kp = K + (size_t)bh * SEQ * HEAD_DIM;
    const float* Vp = V + (size_t)bh * SEQ * HEAD_DIM;

    // load Q tile (16x64 floats = 256 float4, one per thread)
    {
        int qi = t >> 4, d0 = (t & 15) * 4;
        *(float4*)&Qs[qi][d0] = *(const float4*)&Qp[qi * HEAD_DIM + d0];
    }
    if (t < TQ) { m_run[t] = -1e30f; l_run[t] = 0.f; }

    const int qi_c = t >> 4;          // accumulator mapping: (query, 4 dims)
    const int d0_c = (t & 15) * 4;
    float acc0 = 0.f, acc1 = 0.f, acc2 = 0.f, acc3 = 0.f;

    const int qmax = q0 + TQ - 1;
    for (int kb = 0; kb <= qmax; kb += KB) {
        __syncthreads();              // LDS reuse barrier (also covers Qs init)
        // cooperative K/V tile load: 64x64 floats each; fully coalesced
        #pragma unroll
        for (int i = 0; i < 4; ++i) {
            int u = t + 256 * i;
            int j = u >> 4;           // 0..63
            int d0 = (u & 15) * 4;    // 0..60
            *(float4*)&Ks[j][d0] = *(const float4*)&Kp[(size_t)(kb + j) * HEAD_DIM + d0];
            *(float4*)&Vs[j][d0] = *(const float4*)&Vp[(size_t)(kb + j) * HEAD_DIM + d0];
        }
        __syncthreads();

        // Phase A: scores S[qi][kj] = (q . k) * 0.125, causal-masked
        {
            int qi = t >> 4;
            #pragma unroll
            for (int r = 0; r < 4; ++r) {
                int kj = (t & 15) + 16 * r;
                float s = 0.f;
                #pragma unroll
                for (int d = 0; d < HEAD_DIM; d += 4) {
                    float4 q4 = *(const float4*)&Qs[qi][d];
                    float4 k4 = *(const float4*)&Ks[kj][d];
                    s += q4.x * k4.x + q4.y * k4.y + q4.z * k4.z + q4.w * k4.w;
                }
                s *= 0.125f;
                if (kb + kj > q0 + qi) s = -1e30f;
                Sc[qi][kj] = s;
            }
        }
        __syncthreads();

        // Phase B: online softmax update, one thread per query row
        if (t < TQ) {
            float mb = -1e30f;
            for (int kj = 0; kj < KB; ++kj) mb = fmaxf(mb, Sc[t][kj]);
            float mo = m_run[t];
            float mn = fmaxf(mo, mb);
            float a  = __expf(mo - mn);
            float sum = 0.f;
            for (int kj = 0; kj < KB; ++kj) {
                float p = __expf(Sc[t][kj] - mn);
                Sc[t][kj] = p;
                sum += p;
            }
            m_run[t]  = mn;
            l_run[t]  = l_run[t] * a + sum;
            alpha_s[t] = a;
        }
        __syncthreads();

        // Phase C: ctx = ctx*alpha + P @ V
        float a = alpha_s[qi_c];
        acc0 *= a; acc1 *= a; acc2 *= a; acc3 *= a;
        #pragma unroll
        for (int kj = 0; kj < KB; ++kj) {
            float p  = Sc[qi_c][kj];                     // broadcast within 16 lanes
            float4 v = *(const float4*)&Vs[kj][d0_c];
            acc0 += p * v.x; acc1 += p * v.y; acc2 += p * v.z; acc3 += p * v.w;
        }
    }

    float inv_l = 1.f / l_run[qi_c];
    int b = bh >> 4;                  // bh = b*H + h
    int h = bh & 15;
    int s_idx = q0 + qi_c;
    float* out = ctx + (size_t)(b * SEQ + s_idx) * DIM + h * HEAD_DIM + d0_c;
    float4 r;
    r.x = acc0 * inv_l; r.y = acc1 * inv_l; r.z = acc2 * inv_l; r.w = acc3 * inv_l;
    *(float4*)out = r;
}

// ---------------- launch ----------------
extern "C" void kernel_launch(void* const* d_in, const int* in_sizes, int n_in,
                              void* d_out, int out_size, void* d_ws, size_t ws_size,
                              hipStream_t stream) {
    const float* x  = (const float*)d_in[0];
    const float* Wq = (const float*)d_in[1];
    const float* bq = (const float*)d_in[2];
    const float* Wk = (const float*)d_in[3];
    const float* bk = (const float*)d_in[4];
    const float* Wv = (const float*)d_in[5];
    const float* bv = (const float*)d_in[6];
    const float* Wo = (const float*)d_in[7];
    const float* bo = (const float*)d_in[8];
    float* out = (float*)d_out;

    float* q_ws   = (float*)d_ws;                        // [B,H,S,64] 16 MB
    float* k_ws   = q_ws + (size_t)M_ROWS * DIM;         // 16 MB
    float* v_ws   = k_ws + (size_t)M_ROWS * DIM;         // 16 MB
    float* ctx_ws = v_ws + (size_t)M_ROWS * DIM;         // [B,S,DIM] 16 MB

    dim3 ggrid(DIM / TN, M_ROWS / TM);   // (16, 64)
    gemm_bias<<<ggrid, 256, 0, stream>>>(x, Wq, bq, q_ws, M_ROWS, DIM, DIM, 1);
    gemm_bias<<<ggrid, 256, 0, stream>>>(x, Wk, bk, k_ws, M_ROWS, DIM, DIM, 1);
    gemm_bias<<<ggrid, 256, 0, stream>>>(x, Wv, bv, v_ws, M_ROWS, DIM, DIM, 1);

    int nblk = BATCH * NUM_HEADS * (SEQ / TQ);           // 4096
    attn<<<nblk, 256, 0, stream>>>(q_ws, k_ws, v_ws, ctx_ws);

    gemm_bias<<<ggrid, 256, 0, stream>>>(ctx_ws, Wo, bo, out, M_ROWS, DIM, DIM, 0);
}

// Round 2
// 262.130 us; speedup vs baseline: 7.0392x; 7.0392x over previous
//
#include <hip/hip_runtime.h>
#include <hip/hip_bf16.h>

#define DIM 1024
#define NUM_HEADS 16
#define HEAD_DIM 64
#define BATCH 2
#define SEQ 2048
#define M_ROWS (BATCH * SEQ)   // 4096

typedef short bh8 __attribute__((ext_vector_type(8)));   // 8 bf16 (4 VGPRs)
typedef float f32x4 __attribute__((ext_vector_type(4)));

__device__ __forceinline__ ushort f2bf(float f) {
    union { float f; unsigned u; } v; v.f = f;
    unsigned u = v.u;
    unsigned r = (u + 0x7FFFu + ((u >> 16) & 1u)) >> 16;
    return (ushort)r;
}

// ---------------- cast x: fp32 -> bf16 ----------------
__global__ __launch_bounds__(256) void cast_x(const float* __restrict__ in,
                                              ushort* __restrict__ out, int n4) {
    int i = blockIdx.x * 256 + threadIdx.x;
    if (i < n4) {
        float4 v = ((const float4*)in)[i];
        ushort4 o;
        o.x = f2bf(v.x); o.y = f2bf(v.y); o.z = f2bf(v.z); o.w = f2bf(v.w);
        ((ushort4*)out)[i] = o;
    }
}

// ---------------- transpose+cast W [K,N] fp32 -> Wt [N,K] bf16 ----------------
__global__ __launch_bounds__(256) void transpose_cast(const float* __restrict__ W,
                                                      ushort* __restrict__ Wt) {
    __shared__ float tile[32][33];
    const int t = threadIdx.x;
    const int tx = t & 31, ty = t >> 5;            // ty 0..7
    const int k0 = blockIdx.y * 32, n0 = blockIdx.x * 32;
    #pragma unroll
    for (int i = 0; i < 4; ++i)
        tile[ty + 8 * i][tx] = W[(size_t)(k0 + ty + 8 * i) * DIM + n0 + tx];
    __syncthreads();
    #pragma unroll
    for (int i = 0; i < 4; ++i)
        Wt[(size_t)(n0 + ty + 8 * i) * DIM + k0 + tx] = f2bf(tile[tx][ty + 8 * i]);
}

// ---------------- MFMA GEMM: C = A[M,K] @ Bt[N,K]^T + bias ----------------
// mode 0: fp32 row-major [M,N] out
// mode 1: bf16 head layout [B,H,S,64] out        (Q, K)
// mode 3: bf16 transposed head layout [B,H,64,S] (V)
#define GTM 128
#define GTN 64
#define GBK 64
#define LDK 72

__global__ __launch_bounds__(256) void gemm_mfma(
    const ushort* __restrict__ A, const ushort* __restrict__ Bt,
    const float* __restrict__ bias, void* __restrict__ Cout,
    int M, int N, int K, int mode)
{
    __shared__ alignas(16) ushort As[GTM * LDK];   // 18432 B
    __shared__ alignas(16) ushort Bs[GTN * LDK];   //  9216 B
    const int t = threadIdx.x;
    const int lane = t & 63, wave = t >> 6;
    const int col = lane & 15, quad = lane >> 4;
    const int m0 = blockIdx.y * GTM, n0 = blockIdx.x * GTN;
    const int wm = (wave & 1) * 64, wn = (wave >> 1) * 32;
    f32x4 acc[4][2] = {};

    for (int k0 = 0; k0 < K; k0 += GBK) {
        __syncthreads();
        #pragma unroll
        for (int i = 0; i < 4; ++i) {              // A: 1024 chunks
            int c = i * 256 + t;
            int row = c >> 3, ko = (c & 7) * 8;
            *(uint4*)&As[row * LDK + ko] = *(const uint4*)&A[(size_t)(m0 + row) * K + k0 + ko];
        }
        #pragma unroll
        for (int i = 0; i < 2; ++i) {              // B: 512 chunks
            int c = i * 256 + t;
            int row = c >> 3, ko = (c & 7) * 8;
            *(uint4*)&Bs[row * LDK + ko] = *(const uint4*)&Bt[(size_t)(n0 + row) * K + k0 + ko];
        }
        __syncthreads();
        #pragma unroll
        for (int kk = 0; kk < 2; ++kk) {
            int koff = kk * 32 + quad * 8;
            bh8 af[4], bfr[2];
            #pragma unroll
            for (int mi = 0; mi < 4; ++mi)
                af[mi] = *(const bh8*)&As[(wm + mi * 16 + col) * LDK + koff];
            #pragma unroll
            for (int ni = 0; ni < 2; ++ni)
                bfr[ni] = *(const bh8*)&Bs[(wn + ni * 16 + col) * LDK + koff];
            #pragma unroll
            for (int mi = 0; mi < 4; ++mi)
                #pragma unroll
                for (int ni = 0; ni < 2; ++ni)
                    acc[mi][ni] = __builtin_amdgcn_mfma_f32_16x16x32_bf16(
                        af[mi], bfr[ni], acc[mi][ni], 0, 0, 0);
        }
    }

    if (mode == 0) {
        float* C = (float*)Cout;
        #pragma unroll
        for (int mi = 0; mi < 4; ++mi)
            #pragma unroll
            for (int ni = 0; ni < 2; ++ni) {
                int n = n0 + wn + ni * 16 + col;
                float bv = bias[n];
                #pragma unroll
                for (int r = 0; r < 4; ++r) {
                    int m = m0 + wm + mi * 16 + quad * 4 + r;
                    C[(size_t)m * N + n] = acc[mi][ni][r] + bv;
                }
            }
    } else if (mode == 1) {
        ushort* C = (ushort*)Cout;
        #pragma unroll
        for (int mi = 0; mi < 4; ++mi)
            #pragma unroll
            for (int ni = 0; ni < 2; ++ni) {
                int n = n0 + wn + ni * 16 + col;
                float bv = bias[n];
                int h = n >> 6, d = n & 63;
                #pragma unroll
                for (int r = 0; r < 4; ++r) {
                    int m = m0 + wm + mi * 16 + quad * 4 + r;
                    int b = m >> 11, s = m & (SEQ - 1);
                    C[(((size_t)(b * NUM_HEADS + h) * SEQ + s) << 6) + d] =
                        f2bf(acc[mi][ni][r] + bv);
                }
            }
    } else {
        // mode 3: V transposed [B,H,64,S] via LDS transpose (reuse As: need 64*136=8704 <= 9216)
        ushort* C = (ushort*)Cout;
        __syncthreads();
        ushort* LT = As;
        #pragma unroll
        for (int mi = 0; mi < 4; ++mi)
            #pragma unroll
            for (int ni = 0; ni < 2; ++ni) {
                int nl = wn + ni * 16 + col;
                float bv = bias[n0 + nl];
                #pragma unroll
                for (int r = 0; r < 4; ++r) {
                    int ml = wm + mi * 16 + quad * 4 + r;
                    LT[nl * 136 + ml] = f2bf(acc[mi][ni][r] + bv);
                }
            }
        __syncthreads();
        int b = m0 >> 11, s_base = m0 & (SEQ - 1);
        int h = n0 >> 6;
        #pragma unroll
        for (int i = 0; i < 4; ++i) {              // 1024 chunks of 8
            int c = i * 256 + t;
            int row = c >> 4, mo = (c & 15) * 8;
            uint4 v = *(const uint4*)&LT[row * 136 + mo];
            *(uint4*)&C[(((size_t)(b * NUM_HEADS + h) * HEAD_DIM + row) << 11) + s_base + mo] = v;
        }
    }
}

// ---------------- MFMA flash attention ----------------
// Q,K: [B,H,S,64] bf16; Vt: [B,H,64,S] bf16; ctx out: [B,S,DIM] bf16.
// Block = (bh, 64-query tile); 4 waves x 16 queries.
// Per key-block (64 keys): St = K @ Q^T (D: row=key, col=query), column softmax,
// P^T -> per-wave LDS [q][key], ctx^T += V^T @ P^T (D: row=d, col=query).
#define PSTR 72

__global__ __launch_bounds__(256) void attn_mfma(
    const ushort* __restrict__ Qg, const ushort* __restrict__ Kg,
    const ushort* __restrict__ Vtg, ushort* __restrict__ ctx)
{
    __shared__ alignas(16) ushort Ks[64 * PSTR];        // 9216 B
    __shared__ alignas(16) ushort Vt[64 * PSTR];        // 9216 B
    __shared__ alignas(16) ushort Ps[4][16 * PSTR];     // 9216 B

    const int t = threadIdx.x;
    const int lane = t & 63, wave = t >> 6;
    const int col = lane & 15, quad = lane >> 4;
    const int qt = blockIdx.x & 31;
    const int bh = blockIdx.x >> 5;
    const int q0 = qt * 64;
    const int qw = q0 + wave * 16;
    const int b = bh >> 4, h = bh & 15;

    // Q fragments (B-operand): elem j = Q[qw+col][kk*32+quad*8+j]
    bh8 qf[2];
    {
        const ushort* Qp = Qg + (((size_t)bh * SEQ + qw + col) << 6) + quad * 8;
        qf[0] = *(const bh8*)(Qp);
        qf[1] = *(const bh8*)(Qp + 32);
    }

    float m_run = -1e30f, l_run = 0.f;
    f32x4 O[4] = {};

    const ushort* Kp = Kg + ((size_t)bh * SEQ << 6);
    const ushort* Vp = Vtg + ((size_t)bh * HEAD_DIM * SEQ);
    const float SCL = 0.18033688011116016f;   // 0.125 * log2(e)

    const int kb_end = q0 + 64;
    for (int kb = 0; kb < kb_end; kb += 64) {
        __syncthreads();
        #pragma unroll
        for (int i = 0; i < 2; ++i) {          // 512 chunks each
            int c = i * 256 + t;
            int row = c >> 3, ko = (c & 7) * 8;
            *(uint4*)&Ks[row * PSTR + ko] = *(const uint4*)&Kp[((size_t)(kb + row) << 6) + ko];
            *(uint4*)&Vt[row * PSTR + ko] = *(const uint4*)&Vp[((size_t)row << 11) + kb + ko];
        }
        __syncthreads();

        // St = K @ Q^T
        f32x4 St[4] = {};
        #pragma unroll
        for (int kk = 0; kk < 2; ++kk) {
            int koff = kk * 32 + quad * 8;
            #pragma unroll
            for (int kt = 0; kt < 4; ++kt) {
                bh8 kf = *(const bh8*)&Ks[(kt * 16 + col) * PSTR + koff];
                St[kt] = __builtin_amdgcn_mfma_f32_16x16x32_bf16(kf, qf[kk], St[kt], 0, 0, 0);
            }
        }

        // mask + scale (log2 domain), column (=query) stats
        float sv[4][4];
        const int q_abs = qw + col;
        float mb = -1e30f;
        #pragma unroll
        for (int kt = 0; kt < 4; ++kt)
            #pragma unroll
            for (int r = 0; r < 4; ++r) {
                int key = kb + kt * 16 + quad * 4 + r;
                float s = (key <= q_abs) ? St[kt][r] * SCL : -1e30f;
                sv[kt][r] = s;
                mb = fmaxf(mb, s);
            }
        mb = fmaxf(mb, __shfl_xor(mb, 16));
        mb = fmaxf(mb, __shfl_xor(mb, 32));
        float mn = fmaxf(m_run, mb);
        float alpha = exp2f(m_run - mn);
        float lb = 0.f;
        ushort pb[4][4];
        #pragma unroll
        for (int kt = 0; kt < 4; ++kt)
            #pragma unroll
            for (int r = 0; r < 4; ++r) {
                float p = exp2f(sv[kt][r] - mn);
                lb += p;
                pb[kt][r] = f2bf(p);
            }
        lb += __shfl_xor(lb, 16);
        lb += __shfl_xor(lb, 32);
        m_run = mn;
        l_run = l_run * alpha + lb;

        // write P^T to per-wave LDS as Ps[q][key]
        ushort* Pw = Ps[wave];
        #pragma unroll
        for (int kt = 0; kt < 4; ++kt)
            #pragma unroll
            for (int r = 0; r < 4; ++r)
                Pw[col * PSTR + kt * 16 + quad * 4 + r] = pb[kt][r];

        #pragma unroll
        for (int dt = 0; dt < 4; ++dt)
            #pragma unroll
            for (int r = 0; r < 4; ++r)
                O[dt][r] *= alpha;

        // ctx^T += V^T @ P^T
        #pragma unroll
        for (int kk = 0; kk < 2; ++kk) {
            int koff = kk * 32 + quad * 8;
            bh8 pf = *(const bh8*)&Pw[col * PSTR + koff];
            #pragma unroll
            for (int dt = 0; dt < 4; ++dt) {
                bh8 vf = *(const bh8*)&Vt[(dt * 16 + col) * PSTR + koff];
                O[dt] = __builtin_amdgcn_mfma_f32_16x16x32_bf16(vf, pf, O[dt], 0, 0, 0);
            }
        }
    }

    // epilogue: O (row=d, col=q) -> per-wave LDS [q][d] -> coalesced global
    float inv_l = 1.f / l_run;
    ushort* Pw = Ps[wave];
    #pragma unroll
    for (int dt = 0; dt < 4; ++dt)
        #pragma unroll
        for (int r = 0; r < 4; ++r)
            Pw[col * PSTR + dt * 16 + quad * 4 + r] = f2bf(O[dt][r] * inv_l);
    #pragma unroll
    for (int i = 0; i < 2; ++i) {             // 128 chunks of 8, 2/lane
        int c = i * 64 + lane;
        int row = c >> 3, ko = (c & 7) * 8;
        uint4 v = *(const uint4*)&Pw[row * PSTR + ko];
        *(uint4*)&ctx[((size_t)(b * SEQ) + qw + row) * DIM + (h << 6) + ko] = v;
    }
}

// ---------------- launch ----------------
extern "C" void kernel_launch(void* const* d_in, const int* in_sizes, int n_in,
                              void* d_out, int out_size, void* d_ws, size_t ws_size,
                              hipStream_t stream) {
    const float* x  = (const float*)d_in[0];
    const float* Wq = (const float*)d_in[1];
    const float* bq = (const float*)d_in[2];
    const float* Wk = (const float*)d_in[3];
    const float* bk = (const float*)d_in[4];
    const float* Wv = (const float*)d_in[5];
    const float* bv = (const float*)d_in[6];
    const float* Wo = (const float*)d_in[7];
    const float* bo = (const float*)d_in[8];
    float* out = (float*)d_out;

    ushort* x_bf   = (ushort*)d_ws;              // 4M elems
    ushort* wq_t   = x_bf + 4194304;             // 1M each
    ushort* wk_t   = wq_t + 1048576;
    ushort* wv_t   = wk_t + 1048576;
    ushort* wo_t   = wv_t + 1048576;
    ushort* q_ws   = wo_t + 1048576;             // [B,H,S,64] 4M
    ushort* k_ws   = q_ws + 4194304;
    ushort* vt_ws  = k_ws + 4194304;             // [B,H,64,S] 4M
    ushort* ctx_ws = vt_ws + 4194304;            // [B,S,DIM]  4M

    cast_x<<<4096, 256, 0, stream>>>(x, x_bf, (M_ROWS * DIM) / 4);
    dim3 tgrid(32, 32);
    transpose_cast<<<tgrid, 256, 0, stream>>>(Wq, wq_t);
    transpose_cast<<<tgrid, 256, 0, stream>>>(Wk, wk_t);
    transpose_cast<<<tgrid, 256, 0, stream>>>(Wv, wv_t);
    transpose_cast<<<tgrid, 256, 0, stream>>>(Wo, wo_t);

    dim3 ggrid(DIM / GTN, M_ROWS / GTM);         // (16, 32)
    gemm_mfma<<<ggrid, 256, 0, stream>>>(x_bf, wq_t, bq, q_ws,  M_ROWS, DIM, DIM, 1);
    gemm_mfma<<<ggrid, 256, 0, stream>>>(x_bf, wk_t, bk, k_ws,  M_ROWS, DIM, DIM, 1);
    gemm_mfma<<<ggrid, 256, 0, stream>>>(x_bf, wv_t, bv, vt_ws, M_ROWS, DIM, DIM, 3);

    attn_mfma<<<BATCH * NUM_HEADS * (SEQ / 64), 256, 0, stream>>>(q_ws, k_ws, vt_ws, ctx_ws);

    gemm_mfma<<<ggrid, 256, 0, stream>>>(ctx_ws, wo_t, bo, out, M_ROWS, DIM, DIM, 0);
}

// Round 3
// 206.392 us; speedup vs baseline: 8.9402x; 1.2701x over previous
//
#include <hip/hip_runtime.h>
#include <hip/hip_bf16.h>

#define DIM 1024
#define NUM_HEADS 16
#define HEAD_DIM 64
#define BATCH 2
#define SEQ 2048
#define M_ROWS (BATCH * SEQ)   // 4096

typedef short bh8 __attribute__((ext_vector_type(8)));   // 8 bf16 (4 VGPRs)
typedef float f32x4 __attribute__((ext_vector_type(4)));

__device__ __forceinline__ ushort f2bf(float f) {
    union { float f; unsigned u; } v; v.f = f;
    unsigned u = v.u;
    unsigned r = (u + 0x7FFFu + ((u >> 16) & 1u)) >> 16;
    return (ushort)r;
}

__device__ __forceinline__ ushort2 pk_bf16(float a, float b) {
#if __has_builtin(__builtin_amdgcn_cvt_pk_bf16_f32)
    auto r = __builtin_amdgcn_cvt_pk_bf16_f32(a, b);
    ushort2 o; __builtin_memcpy(&o, &r, 4); return o;
#else
    ushort2 o; o.x = f2bf(a); o.y = f2bf(b); return o;
#endif
}

// async global->LDS 16B copy; l must be wave-uniform (HW: base + lane*16)
__device__ __forceinline__ void async_cp16(const ushort* g, ushort* l) {
    __builtin_amdgcn_global_load_lds(
        (const __attribute__((address_space(1))) void*)(uintptr_t)g,
        (__attribute__((address_space(3))) void*)(uint32_t)(uintptr_t)l,
        16, 0, 0);
}

// ---------------- cast x: fp32 -> bf16 ----------------
__global__ __launch_bounds__(256) void cast_x(const float* __restrict__ in,
                                              ushort* __restrict__ out, int n4) {
    int i = blockIdx.x * 256 + threadIdx.x;
    if (i < n4) {
        float4 v = ((const float4*)in)[i];
        ushort4 o;
        o.x = f2bf(v.x); o.y = f2bf(v.y); o.z = f2bf(v.z); o.w = f2bf(v.w);
        ((ushort4*)out)[i] = o;
    }
}

// ---------------- transpose+cast W [K,N] fp32 -> Wt [N,K] bf16 ----------------
__global__ __launch_bounds__(256) void transpose_cast(const float* __restrict__ W,
                                                      ushort* __restrict__ Wt) {
    __shared__ float tile[32][33];
    const int t = threadIdx.x;
    const int tx = t & 31, ty = t >> 5;            // ty 0..7
    const int k0 = blockIdx.y * 32, n0 = blockIdx.x * 32;
    #pragma unroll
    for (int i = 0; i < 4; ++i)
        tile[ty + 8 * i][tx] = W[(size_t)(k0 + ty + 8 * i) * DIM + n0 + tx];
    __syncthreads();
    #pragma unroll
    for (int i = 0; i < 4; ++i)
        Wt[(size_t)(n0 + ty + 8 * i) * DIM + k0 + tx] = f2bf(tile[tx][ty + 8 * i]);
}

// ---------------- shared MFMA GEMM core ----------------
// C = A[M,1024] @ Bt[N,1024]^T, tile 128x64, BK=64.
// LDS dense + xor swizzle: chunk (16B) at row r, logical c stored at phys c^(r&7).
#define GTM 128
#define GTN 64
#define GBK 64

__device__ __forceinline__ void gemm_core(
    const ushort* __restrict__ A, const ushort* __restrict__ Bt,
    ushort* smem, int m0, int n0, int t, f32x4 acc[4][2])
{
    ushort* As = smem;          // 128*64 = 8192 ushorts
    ushort* Bs = smem + 8192;   //  64*64 = 4096 ushorts
    const int lane = t & 63, wave = t >> 6;
    const int col = lane & 15, quad = lane >> 4;
    const int wm = (wave & 1) * 64, wn = (wave >> 1) * 32;

    for (int k0 = 0; k0 < DIM; k0 += GBK) {
        __syncthreads();
        #pragma unroll
        for (int j = 0; j < 4; ++j) {              // A: 1024 chunks, 4 issues/wave
            int C = wave * 256 + j * 64 + lane;
            int row = C >> 3;
            int lch = (C & 7) ^ (row & 7);
            async_cp16(&A[(size_t)(m0 + row) * DIM + k0 + lch * 8],
                       &As[(wave * 256 + j * 64) * 8]);
        }
        #pragma unroll
        for (int j = 0; j < 2; ++j) {              // B: 512 chunks, 2 issues/wave
            int C = wave * 128 + j * 64 + lane;
            int row = C >> 3;
            int lch = (C & 7) ^ (row & 7);
            async_cp16(&Bt[(size_t)(n0 + row) * DIM + k0 + lch * 8],
                       &Bs[(wave * 128 + j * 64) * 8]);
        }
        __syncthreads();
        #pragma unroll
        for (int kk = 0; kk < 2; ++kk) {
            bh8 af[4], bfr[2];
            #pragma unroll
            for (int mi = 0; mi < 4; ++mi) {
                int row = wm + mi * 16 + col;
                int ph = ((kk * 4 + quad) ^ (row & 7)) * 8;
                af[mi] = *(const bh8*)&As[row * 64 + ph];
            }
            #pragma unroll
            for (int ni = 0; ni < 2; ++ni) {
                int row = wn + ni * 16 + col;
                int ph = ((kk * 4 + quad) ^ (row & 7)) * 8;
                bfr[ni] = *(const bh8*)&Bs[row * 64 + ph];
            }
            #pragma unroll
            for (int mi = 0; mi < 4; ++mi)
                #pragma unroll
                for (int ni = 0; ni < 2; ++ni)
                    acc[mi][ni] = __builtin_amdgcn_mfma_f32_16x16x32_bf16(
                        af[mi], bfr[ni], acc[mi][ni], 0, 0, 0);
        }
    }
}

// ---------------- fused QKV projection ----------------
// z=0: Q (head layout), z=1: K (head layout), z=2: V (transposed head layout)
__global__ __launch_bounds__(256) void gemm_qkv(
    const ushort* __restrict__ A,
    const ushort* __restrict__ WqT, const ushort* __restrict__ WkT,
    const ushort* __restrict__ WvT,
    const float* __restrict__ bq, const float* __restrict__ bk,
    const float* __restrict__ bv,
    ushort* __restrict__ qo, ushort* __restrict__ ko_, ushort* __restrict__ vo)
{
    __shared__ ushort smem[12288];   // 24 KB
    const int z = blockIdx.z;
    const ushort* Bt = (z == 0) ? WqT : (z == 1) ? WkT : WvT;
    const float* bias = (z == 0) ? bq : (z == 1) ? bk : bv;
    ushort* outp = (z == 0) ? qo : (z == 1) ? ko_ : vo;

    const int t = threadIdx.x;
    const int lane = t & 63, wave = t >> 6;
    const int col = lane & 15, quad = lane >> 4;
    const int m0 = blockIdx.y * GTM, n0 = blockIdx.x * GTN;
    const int wm = (wave & 1) * 64, wn = (wave >> 1) * 32;
    f32x4 acc[4][2] = {};

    gemm_core(A, Bt, smem, m0, n0, t, acc);

    const int b = m0 >> 11, s0 = m0 & (SEQ - 1);
    const int h = n0 >> 6;

    if (z < 2) {
        // head layout [B,H,S,64] via LDS transpose, fully coalesced 16B stores
        __syncthreads();
        ushort* LT = smem;                          // 128 x 72
        #pragma unroll
        for (int mi = 0; mi < 4; ++mi)
            #pragma unroll
            for (int ni = 0; ni < 2; ++ni) {
                int dl = wn + ni * 16 + col;
                float bvv = bias[n0 + dl];
                #pragma unroll
                for (int r = 0; r < 4; ++r) {
                    int ml = wm + mi * 16 + quad * 4 + r;
                    LT[ml * 72 + dl] = f2bf(acc[mi][ni][r] + bvv);
                }
            }
        __syncthreads();
        ushort* Cp = outp + (((size_t)(b * NUM_HEADS + h) * SEQ + s0) << 6);
        #pragma unroll
        for (int i = 0; i < 4; ++i) {
            int c = i * 256 + t;
            int row = c >> 3, ko = (c & 7) * 8;
            *(uint4*)&Cp[row * 64 + ko] = *(const uint4*)&LT[row * 72 + ko];
        }
    } else {
        // V transposed [B,H,64,S] via LDS transpose
        __syncthreads();
        ushort* LT = smem;                          // 64 x 136
        #pragma unroll
        for (int mi = 0; mi < 4; ++mi)
            #pragma unroll
            for (int ni = 0; ni < 2; ++ni) {
                int nl = wn + ni * 16 + col;
                float bvv = bias[n0 + nl];
                #pragma unroll
                for (int r = 0; r < 4; ++r) {
                    int ml = wm + mi * 16 + quad * 4 + r;
                    LT[nl * 136 + ml] = f2bf(acc[mi][ni][r] + bvv);
                }
            }
        __syncthreads();
        ushort* Cp = outp + (((size_t)(b * NUM_HEADS + h) * HEAD_DIM) << 11);
        #pragma unroll
        for (int i = 0; i < 4; ++i) {
            int c = i * 256 + t;
            int row = c >> 4, mo = (c & 15) * 8;
            *(uint4*)&Cp[((size_t)row << 11) + s0 + mo] = *(const uint4*)&LT[row * 136 + mo];
        }
    }
}

// ---------------- output projection: fp32 out ----------------
__global__ __launch_bounds__(256) void gemm_out(
    const ushort* __restrict__ A, const ushort* __restrict__ Bt,
    const float* __restrict__ bias, float* __restrict__ C)
{
    __shared__ ushort smem[12288];
    const int t = threadIdx.x;
    const int lane = t & 63, wave = t >> 6;
    const int col = lane & 15, quad = lane >> 4;
    const int m0 = blockIdx.y * GTM, n0 = blockIdx.x * GTN;
    const int wm = (wave & 1) * 64, wn = (wave >> 1) * 32;
    f32x4 acc[4][2] = {};

    gemm_core(A, Bt, smem, m0, n0, t, acc);

    #pragma unroll
    for (int mi = 0; mi < 4; ++mi)
        #pragma unroll
        for (int ni = 0; ni < 2; ++ni) {
            int n = n0 + wn + ni * 16 + col;
            float bvv = bias[n];
            #pragma unroll
            for (int r = 0; r < 4; ++r) {
                int m = m0 + wm + mi * 16 + quad * 4 + r;
                C[(size_t)m * DIM + n] = acc[mi][ni][r] + bvv;
            }
        }
}

// ---------------- MFMA flash attention (paired q-tiles, balanced) ----------------
#define PSTR 72

__global__ __launch_bounds__(256) void attn_mfma(
    const ushort* __restrict__ Qg, const ushort* __restrict__ Kg,
    const ushort* __restrict__ Vtg, ushort* __restrict__ ctx)
{
    __shared__ ushort Ks[64 * 64];            // 8 KB, swizzled
    __shared__ ushort Vs[64 * 64];            // 8 KB, swizzled
    __shared__ ushort Ps[4][16 * PSTR];       // 9 KB, per-wave P / O staging

    const int t = threadIdx.x;
    const int lane = t & 63, wave = t >> 6;
    const int col = lane & 15, quad = lane >> 4;
    const int pair = blockIdx.x & 15;
    const int bh = blockIdx.x >> 4;
    const int b = bh >> 4, h = bh & 15;
    const ushort* Kp = Kg + ((size_t)bh << 17);
    const ushort* Vp = Vtg + ((size_t)bh << 17);
    ushort* Pw = Ps[wave];
    const float SCL = 0.18033688011116016f;   // 0.125 * log2(e)

    #pragma unroll 1
    for (int phase = 0; phase < 2; ++phase) {
        const int qt = phase ? (31 - pair) : pair;
        const int q0 = qt * 64;
        const int qw = q0 + wave * 16;

        // Q fragments (B-operand): elem j = Q[qw+col][kk*32+quad*8+j]
        bh8 qf0, qf1;
        {
            const ushort* Qp = Qg + ((size_t)bh << 17) + ((size_t)(qw + col) << 6) + quad * 8;
            qf0 = *(const bh8*)(Qp);
            qf1 = *(const bh8*)(Qp + 32);
        }
        float m_run = -1e30f, l_run = 0.f;
        f32x4 O[4] = {};

        #pragma unroll 1
        for (int kb = 0; kb <= q0; kb += 64) {
            __syncthreads();
            #pragma unroll
            for (int j = 0; j < 2; ++j) {     // 512 chunks each, 2 issues/wave
                int C = wave * 128 + j * 64 + lane;
                int row = C >> 3;
                int lch = (C & 7) ^ (row & 7);
                async_cp16(&Kp[((size_t)(kb + row) << 6) + lch * 8],
                           &Ks[(wave * 128 + j * 64) * 8]);
                async_cp16(&Vp[((size_t)row << 11) + kb + lch * 8],
                           &Vs[(wave * 128 + j * 64) * 8]);
            }
            __syncthreads();

            // St = K @ Q^T : D row=key(quad*4+r), col=query
            f32x4 St[4] = {};
            #pragma unroll
            for (int kk = 0; kk < 2; ++kk) {
                bh8 qf = kk ? qf1 : qf0;
                int ph = ((kk * 4 + quad) ^ (col & 7)) * 8;
                #pragma unroll
                for (int kt = 0; kt < 4; ++kt) {
                    bh8 kf = *(const bh8*)&Ks[(kt * 16 + col) * 64 + ph];
                    St[kt] = __builtin_amdgcn_mfma_f32_16x16x32_bf16(kf, qf, St[kt], 0, 0, 0);
                }
            }

            // causal mask: only the diagonal (last) block needs it
            if (kb == q0) {
                const int q_abs = qw + col;
                #pragma unroll
                for (int kt = 0; kt < 4; ++kt)
                    #pragma unroll
                    for (int r = 0; r < 4; ++r)
                        if (kb + kt * 16 + quad * 4 + r > q_abs) St[kt][r] = -1e30f;
            }

            // column (=query) softmax stats, raw-score domain
            float mb = -1e30f;
            #pragma unroll
            for (int kt = 0; kt < 4; ++kt) {
                float m01 = fmaxf(St[kt][0], St[kt][1]);
                float m23 = fmaxf(St[kt][2], St[kt][3]);
                mb = fmaxf(mb, fmaxf(m01, m23));
            }
            mb = fmaxf(mb, __shfl_xor(mb, 16));
            mb = fmaxf(mb, __shfl_xor(mb, 32));
            float mn = fmaxf(m_run, mb);
            float alpha = exp2f((m_run - mn) * SCL);
            float negc = -mn * SCL;
            m_run = mn;

            float lb = 0.f;
            #pragma unroll
            for (int kt = 0; kt < 4; ++kt) {
                float p0 = exp2f(fmaf(St[kt][0], SCL, negc));
                float p1 = exp2f(fmaf(St[kt][1], SCL, negc));
                float p2 = exp2f(fmaf(St[kt][2], SCL, negc));
                float p3 = exp2f(fmaf(St[kt][3], SCL, negc));
                lb += (p0 + p1) + (p2 + p3);
                ushort2 a01 = pk_bf16(p0, p1), a23 = pk_bf16(p2, p3);
                ushort4 pk4; pk4.x = a01.x; pk4.y = a01.y; pk4.z = a23.x; pk4.w = a23.y;
                *(ushort4*)&Pw[col * PSTR + kt * 16 + quad * 4] = pk4;   // P^T: [q][key]
            }
            lb += __shfl_xor(lb, 16);
            lb += __shfl_xor(lb, 32);
            l_run = l_run * alpha + lb;

            #pragma unroll
            for (int dt = 0; dt < 4; ++dt)
                #pragma unroll
                for (int r = 0; r < 4; ++r)
                    O[dt][r] *= alpha;

            // ctx^T += V^T @ P^T  (wave-local P: DS ops in-order, no barrier)
            #pragma unroll
            for (int kk = 0; kk < 2; ++kk) {
                int koff = kk * 32 + quad * 8;
                bh8 pf = *(const bh8*)&Pw[col * PSTR + koff];
                int ph = ((kk * 4 + quad) ^ (col & 7)) * 8;
                #pragma unroll
                for (int dt = 0; dt < 4; ++dt) {
                    bh8 vf = *(const bh8*)&Vs[(dt * 16 + col) * 64 + ph];
                    O[dt] = __builtin_amdgcn_mfma_f32_16x16x32_bf16(vf, pf, O[dt], 0, 0, 0);
                }
            }
        }

        // epilogue: O (row=d, col=q) -> per-wave LDS [q][d] -> coalesced global
        float inv_l = 1.f / l_run;
        #pragma unroll
        for (int dt = 0; dt < 4; ++dt) {
            ushort2 a01 = pk_bf16(O[dt][0] * inv_l, O[dt][1] * inv_l);
            ushort2 a23 = pk_bf16(O[dt][2] * inv_l, O[dt][3] * inv_l);
            ushort4 pk4; pk4.x = a01.x; pk4.y = a01.y; pk4.z = a23.x; pk4.w = a23.y;
            *(ushort4*)&Pw[col * PSTR + dt * 16 + quad * 4] = pk4;
        }
        #pragma unroll
        for (int i = 0; i < 2; ++i) {
            int c = i * 64 + lane;
            int row = c >> 3, ko = (c & 7) * 8;
            *(uint4*)&ctx[((size_t)(b * SEQ) + qw + row) * DIM + (h << 6) + ko] =
                *(const uint4*)&Pw[row * PSTR + ko];
        }
    }
}

// ---------------- launch ----------------
extern "C" void kernel_launch(void* const* d_in, const int* in_sizes, int n_in,
                              void* d_out, int out_size, void* d_ws, size_t ws_size,
                              hipStream_t stream) {
    const float* x  = (const float*)d_in[0];
    const float* Wq = (const float*)d_in[1];
    const float* bq = (const float*)d_in[2];
    const float* Wk = (const float*)d_in[3];
    const float* bk = (const float*)d_in[4];
    const float* Wv = (const float*)d_in[5];
    const float* bv = (const float*)d_in[6];
    const float* Wo = (const float*)d_in[7];
    const float* bo = (const float*)d_in[8];
    float* out = (float*)d_out;

    ushort* x_bf   = (ushort*)d_ws;              // 4M elems
    ushort* wq_t   = x_bf + 4194304;             // 1M each
    ushort* wk_t   = wq_t + 1048576;
    ushort* wv_t   = wk_t + 1048576;
    ushort* wo_t   = wv_t + 1048576;
    ushort* q_ws   = wo_t + 1048576;             // [B,H,S,64] 4M
    ushort* k_ws   = q_ws + 4194304;
    ushort* vt_ws  = k_ws + 4194304;             // [B,H,64,S] 4M
    ushort* ctx_ws = vt_ws + 4194304;            // [B,S,DIM]  4M

    cast_x<<<4096, 256, 0, stream>>>(x, x_bf, (M_ROWS * DIM) / 4);
    dim3 tgrid(32, 32);
    transpose_cast<<<tgrid, 256, 0, stream>>>(Wq, wq_t);
    transpose_cast<<<tgrid, 256, 0, stream>>>(Wk, wk_t);
    transpose_cast<<<tgrid, 256, 0, stream>>>(Wv, wv_t);
    transpose_cast<<<tgrid, 256, 0, stream>>>(Wo, wo_t);

    dim3 qkv_grid(DIM / GTN, M_ROWS / GTM, 3);   // (16, 32, 3) = 1536 blocks
    gemm_qkv<<<qkv_grid, 256, 0, stream>>>(x_bf, wq_t, wk_t, wv_t,
                                           bq, bk, bv, q_ws, k_ws, vt_ws);

    attn_mfma<<<BATCH * NUM_HEADS * 16, 256, 0, stream>>>(q_ws, k_ws, vt_ws, ctx_ws);

    dim3 ogrid(DIM / GTN, M_ROWS / GTM);         // (16, 32)
    gemm_out<<<ogrid, 256, 0, stream>>>(ctx_ws, wo_t, bo, out);
}